// Round 1
// baseline (3088.027 us; speedup 1.0000x reference)
//
#include <hip/hip_runtime.h>
#include <math.h>

// ---- problem constants ----
#define NPAD 132                 // padded row stride for 130x130 matrices (16B-aligned rows)
#define MSZ  (130 * 132)
#define TSTEPS 131071            // number of RK4 steps (T-1)
#define LCH 256                  // chunk length
#define NCH 512                  // number of chunks (511 full + 1 of 255)
#define OMEGA 7.2722052166430399e-05f   // 2*pi/86400

// ---- workspace layout (float offsets) ----
#define OFF_A    0
#define OFF_A2   17160
#define OFF_A3   34320
#define OFF_M    51480
#define OFF_C1   68640
#define OFF_C2   85800
#define OFF_P1   102960
#define OFF_P2   120120
#define OFF_MP   137280
#define OFF_C1B  154440
#define OFF_C2B  154570
#define OFF_C3B  154700
#define OFF_AMP  154830
#define OFF_PH   154958
#define OFF_SH   155086
#define OFF_G    155232          // [NCH][130]
#define OFF_XB   221792          // [NCH][130]
#define OFF_GBUF 288352          // [TSTEPS][130]  ~68.2 MB

__device__ __forceinline__ float sigm(float x) { return 1.0f / (1.0f + expf(-x)); }

__device__ __forceinline__ float interp_tout(float t, const float* __restrict__ tv) {
    float u = t * (1.0f / 3600.0f);
    int idx = (int)u;
    if (idx > 1098) idx = 1098;
    float fr = u - (float)idx;
    float v0 = tv[idx];
    return v0 + fr * (tv[idx + 1] - v0);
}

__device__ void mm130(float* __restrict__ dst, const float* __restrict__ X,
                      const float* __restrict__ Y, int tid, int nt) {
    for (int idx = tid; idx < 130 * 130; idx += nt) {
        int r = idx / 130;
        int c = idx - r * 130;
        float acc = 0.0f;
        for (int k = 0; k < 130; ++k)
            acc = fmaf(X[r * NPAD + k], Y[k * NPAD + c], acc);
        dst[r * NPAD + c] = acc;
    }
}

// ---------------- prep: build A, M, C1, C2, M^256, vectors ----------------
__global__ __launch_bounds__(1024) void prep_kernel(
    const float* __restrict__ params, const float* __restrict__ heating,
    const float* __restrict__ Bm, const float* __restrict__ tout_v,
    float* __restrict__ ws, float* __restrict__ out) {
    const int tid = threadIdx.x;
    const int NT = 1024;
    float* A  = ws + OFF_A;
    float* A2 = ws + OFF_A2;
    float* A3 = ws + OFF_A3;
    float* Mm = ws + OFF_M;
    float* C1 = ws + OFF_C1;
    float* C2 = ws + OFF_C2;
    float* P1 = ws + OFF_P1;
    float* P2 = ws + OFF_P2;
    float* MP = ws + OFF_MP;

    // zero all matrix slots (pads must be 0)
    for (int i = tid; i < 9 * MSZ; i += NT) ws[i] = 0.0f;
    __syncthreads();

    // K = sigmoid(params)*1e-5  -> A (off-diag = K, diag fixed next)
    for (int idx = tid; idx < 130 * 130; idx += NT) {
        int r = idx / 130, c = idx - r * 130;
        A[r * NPAD + c] = sigm(params[idx]) * 1e-5f;
    }
    __syncthreads();
    // diag: A[i][i] = -sum_j K[i][j]
    for (int r = tid; r < 130; r += NT) {
        float s = 0.0f;
        for (int k = 0; k < 130; ++k) s += A[r * NPAD + k];
        A[r * NPAD + r] = -s;
    }
    __syncthreads();

    mm130(A2, A, A, tid, NT);  __syncthreads();
    mm130(A3, A, A2, tid, NT); __syncthreads();
    mm130(P2, A, A3, tid, NT); __syncthreads();  // P2 = A^4 (temp)

    // M = I + hA + h^2/2 A2 + h^3/6 A3 + h^4/24 A4
    // C1 = h/6 (I + hA + h^2/2 A2 + h^3/4 A3);  C2 = h/6 (4I + 2hA + h^2/2 A2)
    for (int idx = tid; idx < 130 * 130; idx += NT) {
        int r = idx / 130, c = idx - r * 130;
        int o = r * NPAD + c;
        float eye = (r == c) ? 1.0f : 0.0f;
        float a = A[o], a2 = A2[o], a3 = A3[o], a4 = P2[o];
        Mm[o] = eye + 30.0f * a + 450.0f * a2 + 4500.0f * a3 + 33750.0f * a4;
        C1[o] = 5.0f * eye + 150.0f * a + 2250.0f * a2 + 33750.0f * a3;
        C2[o] = 20.0f * eye + 300.0f * a + 2250.0f * a2;
    }
    __syncthreads();

    // vectors: c1b = C1 * b0, c2b = C2 * b0, c3b = (h/6) b0   (b0 = B[:,0])
    for (int r = tid; r < 130; r += NT) {
        float s1 = 0.0f, s2 = 0.0f;
        for (int k = 0; k < 130; ++k) {
            float b0 = Bm[k * 129];
            s1 = fmaf(C1[r * NPAD + k], b0, s1);
            s2 = fmaf(C2[r * NPAD + k], b0, s2);
        }
        ws[OFF_C1B + r] = s1;
        ws[OFF_C2B + r] = s2;
        ws[OFF_C3B + r] = 5.0f * Bm[r * 129];
    }
    // per-room: amp folds Q_avg and B's room-diagonal entry
    for (int i = tid; i < 128; i += NT) {
        float bd = Bm[(2 + i) * 129 + (1 + i)];
        ws[OFF_AMP + i] = sigm(heating[i * 3]) * 500.0f * bd;
        ws[OFF_PH + i]  = heating[i * 3 + 1];
        ws[OFF_SH + i]  = heating[i * 3 + 2];
    }
    // initial value + output row 0
    float iv = tout_v[0] + 4.0f;
    for (int i = tid; i < 128; i += NT) out[i] = iv;
    for (int r = tid; r < 130; r += NT) ws[OFF_XB + r] = iv;

    // MP = M^256 via 8 squarings (ping-pong P1/P2)
    for (int i = tid; i < MSZ; i += NT) P1[i] = Mm[i];
    __syncthreads();
    for (int it = 0; it < 8; ++it) {
        const float* src = (it & 1) ? P2 : P1;
        float* dst = (it & 1) ? P1 : P2;
        mm130(dst, src, src, tid, NT);
        __syncthreads();
    }
    for (int i = tid; i < MSZ; i += NT) MP[i] = P1[i];  // final in P1 after 8 iters
}

// ---------------- gforce: g_n for all steps (32 steps / block) ----------------
__global__ __launch_bounds__(256) void gforce_kernel(const float* __restrict__ tout_v,
                                                     float* __restrict__ ws) {
    const int tid = threadIdx.x;
    const int n0 = blockIdx.x * 32;
    const float* C1 = ws + OFF_C1;
    const float* C2 = ws + OFF_C2;
    const float* amp = ws + OFF_AMP;
    const float* ph  = ws + OFF_PH;
    const float* sh  = ws + OFF_SH;
    const float* c1b = ws + OFF_C1B;
    const float* c2b = ws + OFF_C2B;
    const float* c3b = ws + OFF_C3B;
    float* g = ws + OFF_GBUF;

    __shared__ __align__(16) float qgT[128][36];  // [room][grid time 0..32]
    __shared__ __align__(16) float qmT[128][36];  // [room][mid  time 0..31]
    __shared__ float tg[33], tm[32];

    // fill q values (65 time points x 128 rooms)
    for (int p = tid; p < 65 * 128; p += 256) {
        int j, i; float t;
        if (p < 33 * 128) { j = p >> 7; i = p & 127; t = (float)(n0 + j) * 30.0f; }
        else { int p2 = p - 33 * 128; j = p2 >> 7; i = p2 & 127; t = (float)(n0 + j) * 30.0f + 15.0f; }
        float v = amp[i] * sigm(sh[i] * sinf(t * OMEGA + ph[i]));
        if (p < 33 * 128) qgT[i][j] = v; else qmT[i][j] = v;
    }
    for (int j = tid; j < 65; j += 256) {
        if (j < 33) tg[j] = interp_tout((float)(n0 + j) * 30.0f, tout_v);
        else        tm[j - 33] = interp_tout((float)(n0 + j - 33) * 30.0f + 15.0f, tout_v);
    }
    __syncthreads();

    // rooms rows r=2..129: thread = (room rr, half of the 32 steps)
    const int rr = tid & 127;
    const int half = tid >> 7;            // 0 or 1
    const int r = rr + 2;
    float acc1[16], acc2[16];
#pragma unroll
    for (int w = 0; w < 16; ++w) { acc1[w] = 0.0f; acc2[w] = 0.0f; }

    for (int k = 0; k < 128; ++k) {
        float c1 = C1[r * NPAD + 2 + k];
        float c2 = C2[r * NPAD + 2 + k];
        const float4* q1p = reinterpret_cast<const float4*>(&qgT[k][half * 16]);
        const float4* q2p = reinterpret_cast<const float4*>(&qmT[k][half * 16]);
#pragma unroll
        for (int w = 0; w < 4; ++w) {
            float4 a = q1p[w];
            float4 b = q2p[w];
            acc1[4 * w + 0] = fmaf(c1, a.x, acc1[4 * w + 0]);
            acc1[4 * w + 1] = fmaf(c1, a.y, acc1[4 * w + 1]);
            acc1[4 * w + 2] = fmaf(c1, a.z, acc1[4 * w + 2]);
            acc1[4 * w + 3] = fmaf(c1, a.w, acc1[4 * w + 3]);
            acc2[4 * w + 0] = fmaf(c2, b.x, acc2[4 * w + 0]);
            acc2[4 * w + 1] = fmaf(c2, b.y, acc2[4 * w + 1]);
            acc2[4 * w + 2] = fmaf(c2, b.z, acc2[4 * w + 2]);
            acc2[4 * w + 3] = fmaf(c2, b.w, acc2[4 * w + 3]);
        }
    }
#pragma unroll
    for (int w = 0; w < 16; ++w) {
        int n = half * 16 + w;
        int ns = n0 + n;
        if (ns < TSTEPS) {
            float val = acc1[w] + acc2[w]
                      + tg[n] * c1b[r] + tm[n] * c2b[r] + tg[n + 1] * c3b[r]
                      + 5.0f * qgT[rr][n + 1];   // C3 room-diagonal term
            g[ns * 130 + r] = val;
        }
    }

    // rows 0,1 (no direct Qf injection but coupled via C1/C2 off-diagonals)
    if (tid < 64) {
        int r2 = tid >> 5;
        int n = tid & 31;
        int ns = n0 + n;
        if (ns < TSTEPS) {
            float acc = 0.0f;
            for (int k = 0; k < 128; ++k) {
                acc = fmaf(C1[r2 * NPAD + 2 + k], qgT[k][n], acc);
                acc = fmaf(C2[r2 * NPAD + 2 + k], qmT[k][n], acc);
            }
            float val = acc + tg[n] * c1b[r2] + tm[n] * c2b[r2] + tg[n + 1] * c3b[r2];
            g[ns * 130 + r2] = val;
        }
    }
}

// ---------------- chunk_accum: G_c = sum M^{L-1-j} g_{cL+j} ----------------
__global__ __launch_bounds__(192) void chunk_accum_kernel(float* __restrict__ ws) {
    const int c = blockIdx.x;
    const int r = threadIdx.x;
    const float* Mm = ws + OFF_M;
    const float* g = ws + OFF_GBUF;
    float* G = ws + OFF_G;

    __shared__ __align__(16) float xs[2][132];
    float4 mr[33];
    if (r < 130) {
#pragma unroll
        for (int q = 0; q < 33; ++q)
            mr[q] = reinterpret_cast<const float4*>(&Mm[r * NPAD])[q];
    } else {
#pragma unroll
        for (int q = 0; q < 33; ++q) mr[q] = make_float4(0.f, 0.f, 0.f, 0.f);
    }
    if (r < 132) { xs[0][r] = 0.0f; xs[1][r] = 0.0f; }
    __syncthreads();

    const int base = c * LCH;
    const int len = min(LCH, TSTEPS - base);
    int cur = 0;
    float gv = (r < 130) ? g[base * 130 + r] : 0.0f;
    for (int j = 0; j < len; ++j) {
        if (r < 130) {
            float gcur = gv;
            if (j + 1 < len) gv = g[(base + j + 1) * 130 + r];
            const float4* xp = reinterpret_cast<const float4*>(xs[cur]);
            float a0 = 0.f, a1 = 0.f, a2 = 0.f, a3 = 0.f;
#pragma unroll
            for (int q = 0; q < 33; ++q) {
                float4 xv = xp[q];
                a0 = fmaf(mr[q].x, xv.x, a0);
                a1 = fmaf(mr[q].y, xv.y, a1);
                a2 = fmaf(mr[q].z, xv.z, a2);
                a3 = fmaf(mr[q].w, xv.w, a3);
            }
            xs[cur ^ 1][r] = (a0 + a1) + (a2 + a3) + gcur;
        }
        __syncthreads();
        cur ^= 1;
    }
    if (r < 130) G[c * 130 + r] = xs[cur][r];
}

// ---------------- boundary: xb[c+1] = M^L xb[c] + G_c (serial, 1 block) --------
__global__ __launch_bounds__(192) void boundary_kernel(float* __restrict__ ws) {
    const int r = threadIdx.x;
    const float* MP = ws + OFF_MP;
    const float* G = ws + OFF_G;
    float* xb = ws + OFF_XB;

    __shared__ __align__(16) float xs[2][132];
    float4 mr[33];
    if (r < 130) {
#pragma unroll
        for (int q = 0; q < 33; ++q)
            mr[q] = reinterpret_cast<const float4*>(&MP[r * NPAD])[q];
    } else {
#pragma unroll
        for (int q = 0; q < 33; ++q) mr[q] = make_float4(0.f, 0.f, 0.f, 0.f);
    }
    if (r < 132) { xs[0][r] = (r < 130) ? xb[r] : 0.0f; xs[1][r] = 0.0f; }
    __syncthreads();

    int cur = 0;
    float gv = (r < 130) ? G[r] : 0.0f;
    for (int c = 0; c < NCH - 1; ++c) {
        if (r < 130) {
            float gcur = gv;
            if (c + 1 < NCH - 1) gv = G[(c + 1) * 130 + r];
            const float4* xp = reinterpret_cast<const float4*>(xs[cur]);
            float a0 = 0.f, a1 = 0.f, a2 = 0.f, a3 = 0.f;
#pragma unroll
            for (int q = 0; q < 33; ++q) {
                float4 xv = xp[q];
                a0 = fmaf(mr[q].x, xv.x, a0);
                a1 = fmaf(mr[q].y, xv.y, a1);
                a2 = fmaf(mr[q].z, xv.z, a2);
                a3 = fmaf(mr[q].w, xv.w, a3);
            }
            float val = (a0 + a1) + (a2 + a3) + gcur;
            xs[cur ^ 1][r] = val;
            xb[(c + 1) * 130 + r] = val;
        }
        __syncthreads();
        cur ^= 1;
    }
}

// ---------------- chunk_emit: regenerate states, write rooms to out ------------
__global__ __launch_bounds__(192) void chunk_emit_kernel(float* __restrict__ ws,
                                                         float* __restrict__ out) {
    const int c = blockIdx.x;
    const int r = threadIdx.x;
    const float* Mm = ws + OFF_M;
    const float* g = ws + OFF_GBUF;
    const float* xb = ws + OFF_XB;

    __shared__ __align__(16) float xs[2][132];
    float4 mr[33];
    if (r < 130) {
#pragma unroll
        for (int q = 0; q < 33; ++q)
            mr[q] = reinterpret_cast<const float4*>(&Mm[r * NPAD])[q];
    } else {
#pragma unroll
        for (int q = 0; q < 33; ++q) mr[q] = make_float4(0.f, 0.f, 0.f, 0.f);
    }
    if (r < 132) { xs[0][r] = (r < 130) ? xb[c * 130 + r] : 0.0f; xs[1][r] = 0.0f; }
    __syncthreads();

    const int base = c * LCH;
    const int len = min(LCH, TSTEPS - base);
    int cur = 0;
    float gv = (r < 130) ? g[base * 130 + r] : 0.0f;
    for (int j = 0; j < len; ++j) {
        if (r < 130) {
            float gcur = gv;
            if (j + 1 < len) gv = g[(base + j + 1) * 130 + r];
            const float4* xp = reinterpret_cast<const float4*>(xs[cur]);
            float a0 = 0.f, a1 = 0.f, a2 = 0.f, a3 = 0.f;
#pragma unroll
            for (int q = 0; q < 33; ++q) {
                float4 xv = xp[q];
                a0 = fmaf(mr[q].x, xv.x, a0);
                a1 = fmaf(mr[q].y, xv.y, a1);
                a2 = fmaf(mr[q].z, xv.z, a2);
                a3 = fmaf(mr[q].w, xv.w, a3);
            }
            float val = (a0 + a1) + (a2 + a3) + gcur;
            xs[cur ^ 1][r] = val;
            if (r >= 2) out[(base + j + 1) * 128 + (r - 2)] = val;
        }
        __syncthreads();
        cur ^= 1;
    }
}

extern "C" void kernel_launch(void* const* d_in, const int* in_sizes, int n_in,
                              void* d_out, int out_size, void* d_ws, size_t ws_size,
                              hipStream_t stream) {
    const float* params  = (const float*)d_in[1];
    const float* heating = (const float*)d_in[2];
    const float* Bm      = (const float*)d_in[3];
    const float* tout_v  = (const float*)d_in[5];
    float* out = (float*)d_out;
    float* ws = (float*)d_ws;

    prep_kernel<<<1, 1024, 0, stream>>>(params, heating, Bm, tout_v, ws, out);
    gforce_kernel<<<4096, 256, 0, stream>>>(tout_v, ws);
    chunk_accum_kernel<<<NCH, 192, 0, stream>>>(ws);
    boundary_kernel<<<1, 192, 0, stream>>>(ws);
    chunk_emit_kernel<<<NCH, 192, 0, stream>>>(ws, out);
}

// Round 2
// 1389.415 us; speedup vs baseline: 2.2225x; 2.2225x over previous
//
#include <hip/hip_runtime.h>
#include <math.h>

// ---- problem constants ----
#define NPAD 132                 // padded row stride for 130x130 matrices (16B-aligned rows)
#define MSZ  (130 * 132)
#define TSTEPS 131071            // number of RK4 steps (T-1)
#define LCH 256                  // chunk length
#define NCH 512                  // number of chunks (511 full + 1 of 255)
#define OMEGA 7.2722052166430399e-05f   // 2*pi/86400

// ---- workspace layout (float offsets) ----
#define OFF_A    0
#define OFF_A2   17160
#define OFF_A3   34320
#define OFF_M    51480
#define OFF_C1   68640
#define OFF_C2   85800
#define OFF_P1   102960
#define OFF_P2   120120
#define OFF_MP   137280
#define OFF_C1B  154440
#define OFF_C2B  154570
#define OFF_C3B  154700
#define OFF_AMP  154830
#define OFF_PH   154958
#define OFF_SH   155086
#define OFF_G    155232          // [NCH][130]
#define OFF_XB   221792          // [NCH][130]
#define OFF_GBUF 288352          // [TSTEPS][130]  ~68.2 MB

__device__ __forceinline__ float sigm(float x) { return 1.0f / (1.0f + expf(-x)); }

__device__ __forceinline__ float interp_tout(float t, const float* __restrict__ tv) {
    float u = t * (1.0f / 3600.0f);
    int idx = (int)u;
    if (idx > 1098) idx = 1098;
    float fr = u - (float)idx;
    float v0 = tv[idx];
    return v0 + fr * (tv[idx + 1] - v0);
}

// ---------------- build_A: A matrix + small vectors ----------------
__global__ __launch_bounds__(256) void build_A_kernel(
    const float* __restrict__ params, const float* __restrict__ heating,
    const float* __restrict__ Bm, const float* __restrict__ tout_v,
    float* __restrict__ ws, float* __restrict__ out) {
    const int tid = threadIdx.x;
    float* A = ws + OFF_A;

    // K = sigmoid(params)*1e-5 -> A (diag fixed below)
    for (int idx = tid; idx < 130 * 130; idx += 256) {
        int r = idx / 130, c = idx - r * 130;
        A[r * NPAD + c] = sigm(params[idx]) * 1e-5f;
    }
    __syncthreads();
    // diag: A[i][i] = -sum_j K[i][j]  (sum includes K_ii currently on the diag)
    for (int r = tid; r < 130; r += 256) {
        float s = 0.0f;
        for (int k = 0; k < 130; ++k) s += A[r * NPAD + k];
        A[r * NPAD + r] = -s;
    }
    // per-room: amp folds Q_avg and B's room-diagonal entry
    for (int i = tid; i < 128; i += 256) {
        float bd = Bm[(2 + i) * 129 + (1 + i)];
        ws[OFF_AMP + i] = sigm(heating[i * 3]) * 500.0f * bd;
        ws[OFF_PH + i]  = heating[i * 3 + 1];
        ws[OFF_SH + i]  = heating[i * 3 + 2];
    }
    // initial value + output row 0 + chunk-boundary x_0
    float iv = tout_v[0] + 4.0f;
    for (int i = tid; i < 128; i += 256) out[i] = iv;
    for (int r = tid; r < 130; r += 256) ws[OFF_XB + r] = iv;
}

// ---------------- mm: dst = X*Y (130x130), one block per output row ----------
__global__ __launch_bounds__(192) void mm_kernel(float* __restrict__ ws,
                                                 int offD, int offX, int offY) {
    const float* X = ws + offX;
    const float* Y = ws + offY;
    float* dst = ws + offD;
    __shared__ float xrow[130];
    const int r = blockIdx.x;
    const int c = threadIdx.x;
    if (c < 130) xrow[c] = X[r * NPAD + c];
    __syncthreads();
    if (c < 130) {
        float acc = 0.0f;
#pragma unroll 5
        for (int k = 0; k < 130; ++k)
            acc = fmaf(xrow[k], Y[k * NPAD + c], acc);
        dst[r * NPAD + c] = acc;
    }
}

// ---------------- combine: M, C1, C2 from A..A4 (elementwise) ----------------
__global__ __launch_bounds__(256) void combine_kernel(float* __restrict__ ws) {
    int idx = blockIdx.x * 256 + threadIdx.x;
    if (idx >= 130 * 130) return;
    int r = idx / 130, c = idx - r * 130;
    int o = r * NPAD + c;
    const float* A  = ws + OFF_A;
    const float* A2 = ws + OFF_A2;
    const float* A3 = ws + OFF_A3;
    const float* A4 = ws + OFF_P2;   // A^4 lives in P2 until squarings start
    float eye = (r == c) ? 1.0f : 0.0f;
    float a = A[o], a2 = A2[o], a3 = A3[o], a4 = A4[o];
    ws[OFF_M  + o] = eye + 30.0f * a + 450.0f * a2 + 4500.0f * a3 + 33750.0f * a4;
    ws[OFF_C1 + o] = 5.0f * eye + 150.0f * a + 2250.0f * a2 + 33750.0f * a3;
    ws[OFF_C2 + o] = 20.0f * eye + 300.0f * a + 2250.0f * a2;
}

// ---------------- vecs: c1b = C1*b0, c2b = C2*b0, c3b = (h/6) b0 -------------
__global__ __launch_bounds__(192) void vecs_kernel(const float* __restrict__ Bm,
                                                   float* __restrict__ ws) {
    const int r = threadIdx.x;
    if (r >= 130) return;
    const float* C1 = ws + OFF_C1;
    const float* C2 = ws + OFF_C2;
    float s1 = 0.0f, s2 = 0.0f;
    for (int k = 0; k < 130; ++k) {
        float b0 = Bm[k * 129];
        s1 = fmaf(C1[r * NPAD + k], b0, s1);
        s2 = fmaf(C2[r * NPAD + k], b0, s2);
    }
    ws[OFF_C1B + r] = s1;
    ws[OFF_C2B + r] = s2;
    ws[OFF_C3B + r] = 5.0f * Bm[r * 129];
}

// ---------------- gforce: g_n for all steps (32 steps / block) ----------------
__global__ __launch_bounds__(256) void gforce_kernel(const float* __restrict__ tout_v,
                                                     float* __restrict__ ws) {
    const int tid = threadIdx.x;
    const int n0 = blockIdx.x * 32;
    const float* C1 = ws + OFF_C1;
    const float* C2 = ws + OFF_C2;
    const float* amp = ws + OFF_AMP;
    const float* ph  = ws + OFF_PH;
    const float* sh  = ws + OFF_SH;
    const float* c1b = ws + OFF_C1B;
    const float* c2b = ws + OFF_C2B;
    const float* c3b = ws + OFF_C3B;
    float* g = ws + OFF_GBUF;

    __shared__ __align__(16) float qgT[128][36];  // [room][grid time 0..32]
    __shared__ __align__(16) float qmT[128][36];  // [room][mid  time 0..31]
    __shared__ float tg[33], tm[32];

    // fill q values (65 time points x 128 rooms)
    for (int p = tid; p < 65 * 128; p += 256) {
        int j, i; float t;
        if (p < 33 * 128) { j = p >> 7; i = p & 127; t = (float)(n0 + j) * 30.0f; }
        else { int p2 = p - 33 * 128; j = p2 >> 7; i = p2 & 127; t = (float)(n0 + j) * 30.0f + 15.0f; }
        float v = amp[i] * sigm(sh[i] * sinf(t * OMEGA + ph[i]));
        if (p < 33 * 128) qgT[i][j] = v; else qmT[i][j] = v;
    }
    for (int j = tid; j < 65; j += 256) {
        if (j < 33) tg[j] = interp_tout((float)(n0 + j) * 30.0f, tout_v);
        else        tm[j - 33] = interp_tout((float)(n0 + j - 33) * 30.0f + 15.0f, tout_v);
    }
    __syncthreads();

    // rooms rows r=2..129: thread = (room rr, half of the 32 steps)
    const int rr = tid & 127;
    const int half = tid >> 7;            // 0 or 1
    const int r = rr + 2;
    float acc1[16], acc2[16];
#pragma unroll
    for (int w = 0; w < 16; ++w) { acc1[w] = 0.0f; acc2[w] = 0.0f; }

    for (int k = 0; k < 128; ++k) {
        float c1 = C1[r * NPAD + 2 + k];
        float c2 = C2[r * NPAD + 2 + k];
        const float4* q1p = reinterpret_cast<const float4*>(&qgT[k][half * 16]);
        const float4* q2p = reinterpret_cast<const float4*>(&qmT[k][half * 16]);
#pragma unroll
        for (int w = 0; w < 4; ++w) {
            float4 a = q1p[w];
            float4 b = q2p[w];
            acc1[4 * w + 0] = fmaf(c1, a.x, acc1[4 * w + 0]);
            acc1[4 * w + 1] = fmaf(c1, a.y, acc1[4 * w + 1]);
            acc1[4 * w + 2] = fmaf(c1, a.z, acc1[4 * w + 2]);
            acc1[4 * w + 3] = fmaf(c1, a.w, acc1[4 * w + 3]);
            acc2[4 * w + 0] = fmaf(c2, b.x, acc2[4 * w + 0]);
            acc2[4 * w + 1] = fmaf(c2, b.y, acc2[4 * w + 1]);
            acc2[4 * w + 2] = fmaf(c2, b.z, acc2[4 * w + 2]);
            acc2[4 * w + 3] = fmaf(c2, b.w, acc2[4 * w + 3]);
        }
    }
#pragma unroll
    for (int w = 0; w < 16; ++w) {
        int n = half * 16 + w;
        int ns = n0 + n;
        if (ns < TSTEPS) {
            float val = acc1[w] + acc2[w]
                      + tg[n] * c1b[r] + tm[n] * c2b[r] + tg[n + 1] * c3b[r]
                      + 5.0f * qgT[rr][n + 1];   // C3 room-diagonal term
            g[ns * 130 + r] = val;
        }
    }

    // rows 0,1 (no direct Qf injection but coupled via C1/C2 off-diagonals)
    if (tid < 64) {
        int r2 = tid >> 5;
        int n = tid & 31;
        int ns = n0 + n;
        if (ns < TSTEPS) {
            float acc = 0.0f;
            for (int k = 0; k < 128; ++k) {
                acc = fmaf(C1[r2 * NPAD + 2 + k], qgT[k][n], acc);
                acc = fmaf(C2[r2 * NPAD + 2 + k], qmT[k][n], acc);
            }
            float val = acc + tg[n] * c1b[r2] + tm[n] * c2b[r2] + tg[n + 1] * c3b[r2];
            g[ns * 130 + r2] = val;
        }
    }
}

// ---------------- chunk_accum: G_c = sum M^{L-1-j} g_{cL+j} ----------------
__global__ __launch_bounds__(192) void chunk_accum_kernel(float* __restrict__ ws) {
    const int c = blockIdx.x;
    const int r = threadIdx.x;
    const float* Mm = ws + OFF_M;
    const float* g = ws + OFF_GBUF;
    float* G = ws + OFF_G;

    __shared__ __align__(16) float xs[2][132];
    float4 mr[33];
    if (r < 130) {
#pragma unroll
        for (int q = 0; q < 33; ++q)
            mr[q] = reinterpret_cast<const float4*>(&Mm[r * NPAD])[q];
    } else {
#pragma unroll
        for (int q = 0; q < 33; ++q) mr[q] = make_float4(0.f, 0.f, 0.f, 0.f);
    }
    if (r < 132) { xs[0][r] = 0.0f; xs[1][r] = 0.0f; }
    __syncthreads();

    const int base = c * LCH;
    const int len = min(LCH, TSTEPS - base);
    int cur = 0;
    float gv = (r < 130) ? g[base * 130 + r] : 0.0f;
    for (int j = 0; j < len; ++j) {
        if (r < 130) {
            float gcur = gv;
            if (j + 1 < len) gv = g[(base + j + 1) * 130 + r];
            const float4* xp = reinterpret_cast<const float4*>(xs[cur]);
            float a0 = 0.f, a1 = 0.f, a2 = 0.f, a3 = 0.f;
#pragma unroll
            for (int q = 0; q < 33; ++q) {
                float4 xv = xp[q];
                a0 = fmaf(mr[q].x, xv.x, a0);
                a1 = fmaf(mr[q].y, xv.y, a1);
                a2 = fmaf(mr[q].z, xv.z, a2);
                a3 = fmaf(mr[q].w, xv.w, a3);
            }
            xs[cur ^ 1][r] = (a0 + a1) + (a2 + a3) + gcur;
        }
        __syncthreads();
        cur ^= 1;
    }
    if (r < 130) G[c * 130 + r] = xs[cur][r];
}

// ---------------- boundary: xb[c+1] = M^L xb[c] + G_c (serial, 1 block) --------
__global__ __launch_bounds__(192) void boundary_kernel(float* __restrict__ ws) {
    const int r = threadIdx.x;
    const float* MP = ws + OFF_MP;
    const float* G = ws + OFF_G;
    float* xb = ws + OFF_XB;

    __shared__ __align__(16) float xs[2][132];
    float4 mr[33];
    if (r < 130) {
#pragma unroll
        for (int q = 0; q < 33; ++q)
            mr[q] = reinterpret_cast<const float4*>(&MP[r * NPAD])[q];
    } else {
#pragma unroll
        for (int q = 0; q < 33; ++q) mr[q] = make_float4(0.f, 0.f, 0.f, 0.f);
    }
    if (r < 132) { xs[0][r] = (r < 130) ? xb[r] : 0.0f; xs[1][r] = 0.0f; }
    __syncthreads();

    int cur = 0;
    float gv = (r < 130) ? G[r] : 0.0f;
    for (int c = 0; c < NCH - 1; ++c) {
        if (r < 130) {
            float gcur = gv;
            if (c + 1 < NCH - 1) gv = G[(c + 1) * 130 + r];
            const float4* xp = reinterpret_cast<const float4*>(xs[cur]);
            float a0 = 0.f, a1 = 0.f, a2 = 0.f, a3 = 0.f;
#pragma unroll
            for (int q = 0; q < 33; ++q) {
                float4 xv = xp[q];
                a0 = fmaf(mr[q].x, xv.x, a0);
                a1 = fmaf(mr[q].y, xv.y, a1);
                a2 = fmaf(mr[q].z, xv.z, a2);
                a3 = fmaf(mr[q].w, xv.w, a3);
            }
            float val = (a0 + a1) + (a2 + a3) + gcur;
            xs[cur ^ 1][r] = val;
            xb[(c + 1) * 130 + r] = val;
        }
        __syncthreads();
        cur ^= 1;
    }
}

// ---------------- chunk_emit: regenerate states, write rooms to out ------------
__global__ __launch_bounds__(192) void chunk_emit_kernel(float* __restrict__ ws,
                                                         float* __restrict__ out) {
    const int c = blockIdx.x;
    const int r = threadIdx.x;
    const float* Mm = ws + OFF_M;
    const float* g = ws + OFF_GBUF;
    const float* xb = ws + OFF_XB;

    __shared__ __align__(16) float xs[2][132];
    float4 mr[33];
    if (r < 130) {
#pragma unroll
        for (int q = 0; q < 33; ++q)
            mr[q] = reinterpret_cast<const float4*>(&Mm[r * NPAD])[q];
    } else {
#pragma unroll
        for (int q = 0; q < 33; ++q) mr[q] = make_float4(0.f, 0.f, 0.f, 0.f);
    }
    if (r < 132) { xs[0][r] = (r < 130) ? xb[c * 130 + r] : 0.0f; xs[1][r] = 0.0f; }
    __syncthreads();

    const int base = c * LCH;
    const int len = min(LCH, TSTEPS - base);
    int cur = 0;
    float gv = (r < 130) ? g[base * 130 + r] : 0.0f;
    for (int j = 0; j < len; ++j) {
        if (r < 130) {
            float gcur = gv;
            if (j + 1 < len) gv = g[(base + j + 1) * 130 + r];
            const float4* xp = reinterpret_cast<const float4*>(xs[cur]);
            float a0 = 0.f, a1 = 0.f, a2 = 0.f, a3 = 0.f;
#pragma unroll
            for (int q = 0; q < 33; ++q) {
                float4 xv = xp[q];
                a0 = fmaf(mr[q].x, xv.x, a0);
                a1 = fmaf(mr[q].y, xv.y, a1);
                a2 = fmaf(mr[q].z, xv.z, a2);
                a3 = fmaf(mr[q].w, xv.w, a3);
            }
            float val = (a0 + a1) + (a2 + a3) + gcur;
            xs[cur ^ 1][r] = val;
            if (r >= 2) out[(base + j + 1) * 128 + (r - 2)] = val;
        }
        __syncthreads();
        cur ^= 1;
    }
}

extern "C" void kernel_launch(void* const* d_in, const int* in_sizes, int n_in,
                              void* d_out, int out_size, void* d_ws, size_t ws_size,
                              hipStream_t stream) {
    const float* params  = (const float*)d_in[1];
    const float* heating = (const float*)d_in[2];
    const float* Bm      = (const float*)d_in[3];
    const float* tout_v  = (const float*)d_in[5];
    float* out = (float*)d_out;
    float* ws = (float*)d_ws;

    build_A_kernel<<<1, 256, 0, stream>>>(params, heating, Bm, tout_v, ws, out);

    // A2 = A*A ; A3 = A*A2 ; A4 = A2*A2 (into P2, consumed by combine)
    mm_kernel<<<130, 192, 0, stream>>>(ws, OFF_A2, OFF_A, OFF_A);
    mm_kernel<<<130, 192, 0, stream>>>(ws, OFF_A3, OFF_A, OFF_A2);
    mm_kernel<<<130, 192, 0, stream>>>(ws, OFF_P2, OFF_A2, OFF_A2);

    combine_kernel<<<67, 256, 0, stream>>>(ws);
    vecs_kernel<<<1, 192, 0, stream>>>(Bm, ws);

    // M^256 by 8 squarings: M->P1(M^2)->P2(M^4)->P1(M^8)->P2(M^16)->P1(M^32)
    //                        ->P2(M^64)->P1(M^128)->MP(M^256)
    mm_kernel<<<130, 192, 0, stream>>>(ws, OFF_P1, OFF_M,  OFF_M);
    mm_kernel<<<130, 192, 0, stream>>>(ws, OFF_P2, OFF_P1, OFF_P1);
    mm_kernel<<<130, 192, 0, stream>>>(ws, OFF_P1, OFF_P2, OFF_P2);
    mm_kernel<<<130, 192, 0, stream>>>(ws, OFF_P2, OFF_P1, OFF_P1);
    mm_kernel<<<130, 192, 0, stream>>>(ws, OFF_P1, OFF_P2, OFF_P2);
    mm_kernel<<<130, 192, 0, stream>>>(ws, OFF_P2, OFF_P1, OFF_P1);
    mm_kernel<<<130, 192, 0, stream>>>(ws, OFF_P1, OFF_P2, OFF_P2);
    mm_kernel<<<130, 192, 0, stream>>>(ws, OFF_MP, OFF_P1, OFF_P1);

    gforce_kernel<<<4096, 256, 0, stream>>>(tout_v, ws);
    chunk_accum_kernel<<<NCH, 192, 0, stream>>>(ws);
    boundary_kernel<<<1, 192, 0, stream>>>(ws);
    chunk_emit_kernel<<<NCH, 192, 0, stream>>>(ws, out);
}

// Round 3
// 685.571 us; speedup vs baseline: 4.5043x; 2.0267x over previous
//
#include <hip/hip_runtime.h>
#include <math.h>

// ---- problem constants ----
#define NPAD 132                 // padded row stride for 130x130 matrices
#define MSZ  (130 * 132)
#define TSTEPS 131071            // number of RK4 steps (T-1)
#define LCH 256                  // chunk length
#define NCH 512                  // number of chunks (511 full + 1 of 255)
#define OMEGA 7.2722052166430399e-05f   // 2*pi/86400

// ---- workspace layout (float offsets) ----
#define OFF_A    0               // A; later reused for M^128
#define OFF_M128 0
#define OFF_A2   17160           // A^2; later reused for C1T (16384 floats)
#define OFF_C1T  17160
#define OFF_A3   34320           // A^3; later reused for C2T
#define OFF_C2T  34320
#define OFF_M    51480
#define OFF_C1   68640
#define OFF_C2   85800
#define OFF_P1   102960
#define OFF_P2   120120
#define OFF_MP   137280          // M^256
#define OFF_M4K  154440          // M^4096
#define OFF_C1B  171600
#define OFF_C2B  171730
#define OFF_C3B  171860
#define OFF_AMP  171990
#define OFF_CPH  172118
#define OFF_SH   172246
#define OFF_SPH  172374
#define OFF_G    172502          // [NCH][130]
#define OFF_S128 239062          // [NCH][130] partial sums at step 128
#define OFF_XB   305622          // [NCH][130] chunk boundaries
#define OFF_XB2  372182          // [2*NCH][130] half-chunk boundaries
#define OFF_SA   505302          // [31][130] superchunk accумs
#define OFF_GBUF 509462          // [TSTEPS][130]

__device__ __forceinline__ float sigm(float x) { return 1.0f / (1.0f + expf(-x)); }

__device__ __forceinline__ float interp_tout(float t, const float* __restrict__ tv) {
    float u = t * (1.0f / 3600.0f);
    int idx = (int)u;
    if (idx > 1098) idx = 1098;
    float fr = u - (float)idx;
    float v0 = tv[idx];
    return v0 + fr * (tv[idx + 1] - v0);
}

// ---------------- build_A: A matrix + small vectors ----------------
__global__ __launch_bounds__(256) void build_A_kernel(
    const float* __restrict__ params, const float* __restrict__ heating,
    const float* __restrict__ Bm, const float* __restrict__ tout_v,
    float* __restrict__ ws, float* __restrict__ out) {
    const int tid = threadIdx.x;
    float* A = ws + OFF_A;

    for (int idx = tid; idx < 130 * 130; idx += 256) {
        int r = idx / 130, c = idx - r * 130;
        A[r * NPAD + c] = sigm(params[idx]) * 1e-5f;
    }
    // zero pads of A (cols 130,131)
    for (int r = tid; r < 130; r += 256) { A[r * NPAD + 130] = 0.f; A[r * NPAD + 131] = 0.f; }
    __syncthreads();
    for (int r = tid; r < 130; r += 256) {
        float s = 0.0f;
        for (int k = 0; k < 130; ++k) s += A[r * NPAD + k];
        A[r * NPAD + r] = -s;
    }
    for (int i = tid; i < 128; i += 256) {
        float bd = Bm[(2 + i) * 129 + (1 + i)];
        ws[OFF_AMP + i] = sigm(heating[i * 3]) * 500.0f * bd;
        float ph = heating[i * 3 + 1];
        ws[OFF_CPH + i] = cosf(ph);
        ws[OFF_SPH + i] = sinf(ph);
        ws[OFF_SH + i]  = heating[i * 3 + 2];
    }
    float iv = tout_v[0] + 4.0f;
    for (int i = tid; i < 128; i += 256) out[i] = iv;
    for (int r = tid; r < 130; r += 256) ws[OFF_XB + r] = iv;
}

// ---------------- mm: dst = X*Y (130x130), one block per output row ----------
__global__ __launch_bounds__(192) void mm_kernel(float* __restrict__ ws,
                                                 int offD, int offX, int offY) {
    const float* X = ws + offX;
    const float* Y = ws + offY;
    float* dst = ws + offD;
    __shared__ float xrow[130];
    const int r = blockIdx.x;
    const int c = threadIdx.x;
    if (c < 130) xrow[c] = X[r * NPAD + c];
    __syncthreads();
    if (c < 130) {
        float acc = 0.0f;
#pragma unroll 5
        for (int k = 0; k < 130; ++k)
            acc = fmaf(xrow[k], Y[k * NPAD + c], acc);
        dst[r * NPAD + c] = acc;
    }
    if (c >= 130 && c < 132) dst[r * NPAD + c] = 0.0f;  // keep pads zero
}

// ---------------- combine: M, C1, C2 from A..A4 (elementwise) ----------------
__global__ __launch_bounds__(256) void combine_kernel(float* __restrict__ ws) {
    int idx = blockIdx.x * 256 + threadIdx.x;
    if (idx >= 130 * 130) return;
    int r = idx / 130, c = idx - r * 130;
    int o = r * NPAD + c;
    const float* A  = ws + OFF_A;
    const float* A2 = ws + OFF_A2;
    const float* A3 = ws + OFF_A3;
    const float* A4 = ws + OFF_P2;
    float eye = (r == c) ? 1.0f : 0.0f;
    float a = A[o], a2 = A2[o], a3 = A3[o], a4 = A4[o];
    ws[OFF_M  + o] = eye + 30.0f * a + 450.0f * a2 + 4500.0f * a3 + 33750.0f * a4;
    ws[OFF_C1 + o] = 5.0f * eye + 150.0f * a + 2250.0f * a2 + 33750.0f * a3;
    ws[OFF_C2 + o] = 20.0f * eye + 300.0f * a + 2250.0f * a2;
    if (c == 0) {  // zero pads of M,C1,C2 rows
        ws[OFF_M + r * NPAD + 130] = 0.f; ws[OFF_M + r * NPAD + 131] = 0.f;
        ws[OFF_C1 + r * NPAD + 130] = 0.f; ws[OFF_C1 + r * NPAD + 131] = 0.f;
        ws[OFF_C2 + r * NPAD + 130] = 0.f; ws[OFF_C2 + r * NPAD + 131] = 0.f;
    }
}

// ---------------- transpose room submatrices: C1T[k][rr] = C1[rr+2][k+2] ------
__global__ __launch_bounds__(256) void transpose_kernel(float* __restrict__ ws) {
    int idx = blockIdx.x * 256 + threadIdx.x;
    if (idx >= 128 * 128) return;
    int kk = idx >> 7, rr = idx & 127;
    ws[OFF_C1T + idx] = ws[OFF_C1 + (rr + 2) * NPAD + (kk + 2)];
    ws[OFF_C2T + idx] = ws[OFF_C2 + (rr + 2) * NPAD + (kk + 2)];
}

// ---------------- vecs: c1b = C1*b0, c2b = C2*b0, c3b = (h/6) b0 -------------
__global__ __launch_bounds__(192) void vecs_kernel(const float* __restrict__ Bm,
                                                   float* __restrict__ ws) {
    const int r = threadIdx.x;
    if (r >= 130) return;
    const float* C1 = ws + OFF_C1;
    const float* C2 = ws + OFF_C2;
    float s1 = 0.0f, s2 = 0.0f;
    for (int k = 0; k < 130; ++k) {
        float b0 = Bm[k * 129];
        s1 = fmaf(C1[r * NPAD + k], b0, s1);
        s2 = fmaf(C2[r * NPAD + k], b0, s2);
    }
    ws[OFF_C1B + r] = s1;
    ws[OFF_C2B + r] = s2;
    ws[OFF_C3B + r] = 5.0f * Bm[r * 129];
}

// ---------------- gforce: g_n for all steps (32 steps / block) ----------------
__global__ __launch_bounds__(256) void gforce_kernel(const float* __restrict__ tout_v,
                                                     float* __restrict__ ws) {
    const int tid = threadIdx.x;
    const int n0 = blockIdx.x * 32;
    const float* C1T = ws + OFF_C1T;
    const float* C2T = ws + OFF_C2T;
    const float* C1 = ws + OFF_C1;
    const float* C2 = ws + OFF_C2;
    const float* amp = ws + OFF_AMP;
    const float* cph = ws + OFF_CPH;
    const float* sph = ws + OFF_SPH;
    const float* sh  = ws + OFF_SH;
    const float* c1b = ws + OFF_C1B;
    const float* c2b = ws + OFF_C2B;
    const float* c3b = ws + OFF_C3B;
    float* g = ws + OFF_GBUF;

    __shared__ __align__(16) float qgT[128][36];
    __shared__ __align__(16) float qmT[128][36];
    __shared__ float tg[33], tm[32];
    __shared__ float sth[65], cth[65];

    // angle + Tout tables (65 time points)
    for (int j = tid; j < 65; j += 256) {
        float t = (j < 33) ? (float)(n0 + j) * 30.0f
                           : (float)(n0 + j - 33) * 30.0f + 15.0f;
        float a = t * OMEGA;
        sth[j] = sinf(a);
        cth[j] = cosf(a);
        if (j < 33) tg[j] = interp_tout(t, tout_v);
        else        tm[j - 33] = interp_tout(t, tout_v);
    }
    __syncthreads();

    // q values: 65 time points x 128 rooms (fast sigmoid, table trig)
    for (int p = tid; p < 65 * 128; p += 256) {
        int j = p >> 7, i = p & 127;
        float s = sth[j] * cph[i] + cth[j] * sph[i];
        float arg = sh[i] * s;
        float v = amp[i] / (1.0f + __expf(-arg));
        if (j < 33) qgT[i][j] = v; else qmT[i][j - 33] = v;
    }
    __syncthreads();

    const int rr = tid & 127;
    const int half = tid >> 7;
    const int r = rr + 2;
    float acc1[16], acc2[16];
#pragma unroll
    for (int w = 0; w < 16; ++w) { acc1[w] = 0.0f; acc2[w] = 0.0f; }

    for (int k = 0; k < 128; ++k) {
        float c1 = C1T[(k << 7) + rr];   // coalesced
        float c2 = C2T[(k << 7) + rr];
        const float4* q1p = reinterpret_cast<const float4*>(&qgT[k][half * 16]);
        const float4* q2p = reinterpret_cast<const float4*>(&qmT[k][half * 16]);
#pragma unroll
        for (int w = 0; w < 4; ++w) {
            float4 a = q1p[w];
            float4 b = q2p[w];
            acc1[4 * w + 0] = fmaf(c1, a.x, acc1[4 * w + 0]);
            acc1[4 * w + 1] = fmaf(c1, a.y, acc1[4 * w + 1]);
            acc1[4 * w + 2] = fmaf(c1, a.z, acc1[4 * w + 2]);
            acc1[4 * w + 3] = fmaf(c1, a.w, acc1[4 * w + 3]);
            acc2[4 * w + 0] = fmaf(c2, b.x, acc2[4 * w + 0]);
            acc2[4 * w + 1] = fmaf(c2, b.y, acc2[4 * w + 1]);
            acc2[4 * w + 2] = fmaf(c2, b.z, acc2[4 * w + 2]);
            acc2[4 * w + 3] = fmaf(c2, b.w, acc2[4 * w + 3]);
        }
    }
#pragma unroll
    for (int w = 0; w < 16; ++w) {
        int n = half * 16 + w;
        int ns = n0 + n;
        if (ns < TSTEPS) {
            float val = acc1[w] + acc2[w]
                      + tg[n] * c1b[r] + tm[n] * c2b[r] + tg[n + 1] * c3b[r]
                      + 5.0f * qgT[rr][n + 1];
            g[ns * 130 + r] = val;
        }
    }

    // rows 0,1
    if (tid < 64) {
        int r2 = tid >> 5;
        int n = tid & 31;
        int ns = n0 + n;
        if (ns < TSTEPS) {
            float acc = 0.0f;
            for (int k = 0; k < 128; ++k) {
                acc = fmaf(C1[r2 * NPAD + 2 + k], qgT[k][n], acc);
                acc = fmaf(C2[r2 * NPAD + 2 + k], qmT[k][n], acc);
            }
            float val = acc + tg[n] * c1b[r2] + tm[n] * c2b[r2] + tg[n + 1] * c3b[r2];
            g[ns * 130 + r2] = val;
        }
    }
}

// ---------------- chunk_accum: G_c (+ S128 partial) ----------------
__global__ __launch_bounds__(192) void chunk_accum_kernel(float* __restrict__ ws) {
    const int c = blockIdx.x;
    const int r = threadIdx.x;
    const float* Mm = ws + OFF_M;
    const float* g = ws + OFF_GBUF;

    __shared__ __align__(16) float xs[2][132];
    float4 mr[33];
    if (r < 130) {
#pragma unroll
        for (int q = 0; q < 33; ++q)
            mr[q] = reinterpret_cast<const float4*>(&Mm[r * NPAD])[q];
    } else {
#pragma unroll
        for (int q = 0; q < 33; ++q) mr[q] = make_float4(0.f, 0.f, 0.f, 0.f);
    }
    if (r < 132) { xs[0][r] = 0.0f; xs[1][r] = 0.0f; }
    __syncthreads();

    const int base = c * LCH;
    const int len = min(LCH, TSTEPS - base);
    int cur = 0;
    float gv = (r < 130) ? g[base * 130 + r] : 0.0f;
    for (int j = 0; j < len; ++j) {
        if (r < 130) {
            float gcur = gv;
            if (j + 1 < len) gv = g[(base + j + 1) * 130 + r];
            const float4* xp = reinterpret_cast<const float4*>(xs[cur]);
            float a0 = 0.f, a1 = 0.f, a2 = 0.f, a3 = 0.f;
#pragma unroll
            for (int q = 0; q < 33; ++q) {
                float4 xv = xp[q];
                a0 = fmaf(mr[q].x, xv.x, a0);
                a1 = fmaf(mr[q].y, xv.y, a1);
                a2 = fmaf(mr[q].z, xv.z, a2);
                a3 = fmaf(mr[q].w, xv.w, a3);
            }
            float val = (a0 + a1) + (a2 + a3) + gcur;
            xs[cur ^ 1][r] = val;
            if (j == 127) ws[OFF_S128 + c * 130 + r] = val;
        }
        __syncthreads();
        cur ^= 1;
    }
    if (r < 130) ws[OFF_G + c * 130 + r] = xs[cur][r];
}

// ---------------- superaccum: SA_s = sum MP^{15-i} G[16s+i], s=0..30 ----------
__global__ __launch_bounds__(192) void superaccum_kernel(float* __restrict__ ws) {
    const int s = blockIdx.x;
    const int r = threadIdx.x;
    const float* MP = ws + OFF_MP;
    const float* G = ws + OFF_G;

    __shared__ __align__(16) float xs[2][132];
    float4 mr[33];
    if (r < 130) {
#pragma unroll
        for (int q = 0; q < 33; ++q)
            mr[q] = reinterpret_cast<const float4*>(&MP[r * NPAD])[q];
    } else {
#pragma unroll
        for (int q = 0; q < 33; ++q) mr[q] = make_float4(0.f, 0.f, 0.f, 0.f);
    }
    if (r < 132) { xs[0][r] = 0.0f; xs[1][r] = 0.0f; }
    __syncthreads();

    int cur = 0;
    for (int i = 0; i < 16; ++i) {
        if (r < 130) {
            const float4* xp = reinterpret_cast<const float4*>(xs[cur]);
            float a0 = 0.f, a1 = 0.f, a2 = 0.f, a3 = 0.f;
#pragma unroll
            for (int q = 0; q < 33; ++q) {
                float4 xv = xp[q];
                a0 = fmaf(mr[q].x, xv.x, a0);
                a1 = fmaf(mr[q].y, xv.y, a1);
                a2 = fmaf(mr[q].z, xv.z, a2);
                a3 = fmaf(mr[q].w, xv.w, a3);
            }
            xs[cur ^ 1][r] = (a0 + a1) + (a2 + a3) + G[(16 * s + i) * 130 + r];
        }
        __syncthreads();
        cur ^= 1;
    }
    if (r < 130) ws[OFF_SA + s * 130 + r] = xs[cur][r];
}

// ---------------- superbound: xb[16(s+1)] = M4K xb[16s] + SA_s (serial) -------
__global__ __launch_bounds__(192) void superbound_kernel(float* __restrict__ ws) {
    const int r = threadIdx.x;
    const float* M4K = ws + OFF_M4K;
    const float* SA = ws + OFF_SA;
    float* xb = ws + OFF_XB;

    __shared__ __align__(16) float xs[2][132];
    float4 mr[33];
    if (r < 130) {
#pragma unroll
        for (int q = 0; q < 33; ++q)
            mr[q] = reinterpret_cast<const float4*>(&M4K[r * NPAD])[q];
    } else {
#pragma unroll
        for (int q = 0; q < 33; ++q) mr[q] = make_float4(0.f, 0.f, 0.f, 0.f);
    }
    if (r < 132) { xs[0][r] = (r < 130) ? xb[r] : 0.0f; xs[1][r] = 0.0f; }
    __syncthreads();

    int cur = 0;
    for (int s = 0; s < 31; ++s) {
        if (r < 130) {
            const float4* xp = reinterpret_cast<const float4*>(xs[cur]);
            float a0 = 0.f, a1 = 0.f, a2 = 0.f, a3 = 0.f;
#pragma unroll
            for (int q = 0; q < 33; ++q) {
                float4 xv = xp[q];
                a0 = fmaf(mr[q].x, xv.x, a0);
                a1 = fmaf(mr[q].y, xv.y, a1);
                a2 = fmaf(mr[q].z, xv.z, a2);
                a3 = fmaf(mr[q].w, xv.w, a3);
            }
            float val = (a0 + a1) + (a2 + a3) + SA[s * 130 + r];
            xs[cur ^ 1][r] = val;
            xb[(16 * s + 16) * 130 + r] = val;
        }
        __syncthreads();
        cur ^= 1;
    }
}

// ---------------- chunkbound: walk 15 chunks within each superchunk ----------
__global__ __launch_bounds__(192) void chunkbound_kernel(float* __restrict__ ws) {
    const int s = blockIdx.x;
    const int r = threadIdx.x;
    const float* MP = ws + OFF_MP;
    const float* G = ws + OFF_G;
    float* xb = ws + OFF_XB;

    __shared__ __align__(16) float xs[2][132];
    float4 mr[33];
    if (r < 130) {
#pragma unroll
        for (int q = 0; q < 33; ++q)
            mr[q] = reinterpret_cast<const float4*>(&MP[r * NPAD])[q];
    } else {
#pragma unroll
        for (int q = 0; q < 33; ++q) mr[q] = make_float4(0.f, 0.f, 0.f, 0.f);
    }
    if (r < 132) { xs[0][r] = (r < 130) ? xb[(16 * s) * 130 + r] : 0.0f; xs[1][r] = 0.0f; }
    __syncthreads();

    int cur = 0;
    for (int i = 0; i < 15; ++i) {
        if (r < 130) {
            const float4* xp = reinterpret_cast<const float4*>(xs[cur]);
            float a0 = 0.f, a1 = 0.f, a2 = 0.f, a3 = 0.f;
#pragma unroll
            for (int q = 0; q < 33; ++q) {
                float4 xv = xp[q];
                a0 = fmaf(mr[q].x, xv.x, a0);
                a1 = fmaf(mr[q].y, xv.y, a1);
                a2 = fmaf(mr[q].z, xv.z, a2);
                a3 = fmaf(mr[q].w, xv.w, a3);
            }
            float val = (a0 + a1) + (a2 + a3) + G[(16 * s + i) * 130 + r];
            xs[cur ^ 1][r] = val;
            xb[(16 * s + i + 1) * 130 + r] = val;
        }
        __syncthreads();
        cur ^= 1;
    }
}

// ---------------- subbound: xb2[2c]=xb[c]; xb2[2c+1]=M128 xb[c]+S128[c] -------
__global__ __launch_bounds__(192) void subbound_kernel(float* __restrict__ ws) {
    const int c = blockIdx.x;
    const int r = threadIdx.x;
    const float* M128 = ws + OFF_M128;
    const float* xb = ws + OFF_XB;
    float* xb2 = ws + OFF_XB2;

    __shared__ __align__(16) float xs[132];
    if (r < 132) xs[r] = (r < 130) ? xb[c * 130 + r] : 0.0f;
    __syncthreads();
    if (r < 130) {
        const float4* xp = reinterpret_cast<const float4*>(xs);
        const float4* mp = reinterpret_cast<const float4*>(&M128[r * NPAD]);
        float a0 = 0.f, a1 = 0.f, a2 = 0.f, a3 = 0.f;
#pragma unroll
        for (int q = 0; q < 33; ++q) {
            float4 m = mp[q];
            float4 xv = xp[q];
            a0 = fmaf(m.x, xv.x, a0);
            a1 = fmaf(m.y, xv.y, a1);
            a2 = fmaf(m.z, xv.z, a2);
            a3 = fmaf(m.w, xv.w, a3);
        }
        xb2[(2 * c) * 130 + r] = xs[r];
        xb2[(2 * c + 1) * 130 + r] = (a0 + a1) + (a2 + a3) + ws[OFF_S128 + c * 130 + r];
    }
}

// ---------------- emit: 1024 half-chunks x <=128 steps ------------------------
__global__ __launch_bounds__(192) void chunk_emit_kernel(float* __restrict__ ws,
                                                         float* __restrict__ out) {
    const int ec = blockIdx.x;
    const int r = threadIdx.x;
    const float* Mm = ws + OFF_M;
    const float* g = ws + OFF_GBUF;
    const float* xb2 = ws + OFF_XB2;

    __shared__ __align__(16) float xs[2][132];
    float4 mr[33];
    if (r < 130) {
#pragma unroll
        for (int q = 0; q < 33; ++q)
            mr[q] = reinterpret_cast<const float4*>(&Mm[r * NPAD])[q];
    } else {
#pragma unroll
        for (int q = 0; q < 33; ++q) mr[q] = make_float4(0.f, 0.f, 0.f, 0.f);
    }
    if (r < 132) { xs[0][r] = (r < 130) ? xb2[ec * 130 + r] : 0.0f; xs[1][r] = 0.0f; }
    __syncthreads();

    const int base = ec * 128;
    const int len = min(128, TSTEPS - base);
    int cur = 0;
    float gv = (r < 130) ? g[base * 130 + r] : 0.0f;
    for (int j = 0; j < len; ++j) {
        if (r < 130) {
            float gcur = gv;
            if (j + 1 < len) gv = g[(base + j + 1) * 130 + r];
            const float4* xp = reinterpret_cast<const float4*>(xs[cur]);
            float a0 = 0.f, a1 = 0.f, a2 = 0.f, a3 = 0.f;
#pragma unroll
            for (int q = 0; q < 33; ++q) {
                float4 xv = xp[q];
                a0 = fmaf(mr[q].x, xv.x, a0);
                a1 = fmaf(mr[q].y, xv.y, a1);
                a2 = fmaf(mr[q].z, xv.z, a2);
                a3 = fmaf(mr[q].w, xv.w, a3);
            }
            float val = (a0 + a1) + (a2 + a3) + gcur;
            xs[cur ^ 1][r] = val;
            if (r >= 2) out[(base + j + 1) * 128 + (r - 2)] = val;
        }
        __syncthreads();
        cur ^= 1;
    }
}

extern "C" void kernel_launch(void* const* d_in, const int* in_sizes, int n_in,
                              void* d_out, int out_size, void* d_ws, size_t ws_size,
                              hipStream_t stream) {
    const float* params  = (const float*)d_in[1];
    const float* heating = (const float*)d_in[2];
    const float* Bm      = (const float*)d_in[3];
    const float* tout_v  = (const float*)d_in[5];
    float* out = (float*)d_out;
    float* ws = (float*)d_ws;

    build_A_kernel<<<1, 256, 0, stream>>>(params, heating, Bm, tout_v, ws, out);

    // A powers: A2 = A*A ; A3 = A*A2 ; A4 = A2*A2 (into P2)
    mm_kernel<<<130, 192, 0, stream>>>(ws, OFF_A2, OFF_A, OFF_A);
    mm_kernel<<<130, 192, 0, stream>>>(ws, OFF_A3, OFF_A, OFF_A2);
    mm_kernel<<<130, 192, 0, stream>>>(ws, OFF_P2, OFF_A2, OFF_A2);

    combine_kernel<<<67, 256, 0, stream>>>(ws);
    vecs_kernel<<<1, 192, 0, stream>>>(Bm, ws);
    transpose_kernel<<<64, 256, 0, stream>>>(ws);  // overwrites A2/A3 with C1T/C2T

    // squarings: M^2..M^4096 (M128 slot overlays dead A)
    mm_kernel<<<130, 192, 0, stream>>>(ws, OFF_P1,   OFF_M,    OFF_M);    // M^2
    mm_kernel<<<130, 192, 0, stream>>>(ws, OFF_P2,   OFF_P1,   OFF_P1);   // M^4
    mm_kernel<<<130, 192, 0, stream>>>(ws, OFF_P1,   OFF_P2,   OFF_P2);   // M^8
    mm_kernel<<<130, 192, 0, stream>>>(ws, OFF_P2,   OFF_P1,   OFF_P1);   // M^16
    mm_kernel<<<130, 192, 0, stream>>>(ws, OFF_P1,   OFF_P2,   OFF_P2);   // M^32
    mm_kernel<<<130, 192, 0, stream>>>(ws, OFF_P2,   OFF_P1,   OFF_P1);   // M^64
    mm_kernel<<<130, 192, 0, stream>>>(ws, OFF_M128, OFF_P2,   OFF_P2);   // M^128
    mm_kernel<<<130, 192, 0, stream>>>(ws, OFF_MP,   OFF_M128, OFF_M128); // M^256
    mm_kernel<<<130, 192, 0, stream>>>(ws, OFF_P1,   OFF_MP,   OFF_MP);   // M^512
    mm_kernel<<<130, 192, 0, stream>>>(ws, OFF_P2,   OFF_P1,   OFF_P1);   // M^1024
    mm_kernel<<<130, 192, 0, stream>>>(ws, OFF_P1,   OFF_P2,   OFF_P2);   // M^2048
    mm_kernel<<<130, 192, 0, stream>>>(ws, OFF_M4K,  OFF_P1,   OFF_P1);   // M^4096

    gforce_kernel<<<4096, 256, 0, stream>>>(tout_v, ws);
    chunk_accum_kernel<<<NCH, 192, 0, stream>>>(ws);
    superaccum_kernel<<<31, 192, 0, stream>>>(ws);
    superbound_kernel<<<1, 192, 0, stream>>>(ws);
    chunkbound_kernel<<<32, 192, 0, stream>>>(ws);
    subbound_kernel<<<NCH, 192, 0, stream>>>(ws);
    chunk_emit_kernel<<<2 * NCH, 192, 0, stream>>>(ws, out);
}

// Round 4
// 535.813 us; speedup vs baseline: 5.7633x; 1.2795x over previous
//
#include <hip/hip_runtime.h>
#include <math.h>

// ---- problem constants ----
#define NPAD 132                 // padded row stride for 130x130 matrices
#define MSZ  (130 * 132)
#define TSTEPS 131071            // number of RK4 steps (T-1)
#define LCH 256                  // chunk length
#define NCH 512                  // number of chunks
#define PERIOD 2880              // steps per day: forcing q(t) exactly periodic
#define OMEGA 7.2722052166430399e-05f   // 2*pi/86400

// ---- workspace layout (float offsets) ----
#define OFF_A    0               // A; reused for M^128 after combine
#define OFF_M128 0
#define OFF_A2   17160           // dead after combine
#define OFF_A3   34320           // dead after combine
#define OFF_M    51480
#define OFF_C1   68640
#define OFF_C2   85800
#define OFF_P1   102960
#define OFF_P2   120120          // holds A^4 until squarings reuse it
#define OFF_MP   137280          // M^256
#define OFF_M4K  154440          // M^4096
#define OFF_C1T  171600          // [128][128] transposed room block
#define OFF_C2T  187984
#define OFF_C1B  204368
#define OFF_C2B  204498
#define OFF_C3B  204628
#define OFF_AMP  204758
#define OFF_CPH  204886
#define OFF_SPH  205014
#define OFF_SH   205142
#define OFF_G    205270          // [NCH][130]
#define OFF_S128 271830          // [NCH][130]
#define OFF_XB   338390          // [NCH][130]
#define OFF_XB2  404950          // [2*NCH][130]
#define OFF_SA   538070          // [31][130]
#define OFF_GP   542100          // [PERIOD][130] periodic forcing part
#define OFF_TT   916500          // float2[131072] (tg, tm) tables

__device__ __forceinline__ float sigm(float x) { return 1.0f / (1.0f + expf(-x)); }

__device__ __forceinline__ float interp_tout(float t, const float* __restrict__ tv) {
    float u = t * (1.0f / 3600.0f);
    int idx = (int)u;
    if (idx > 1098) idx = 1098;
    float fr = u - (float)idx;
    float v0 = tv[idx];
    return v0 + fr * (tv[idx + 1] - v0);
}

// ---------------- build_A: A matrix + small vectors ----------------
__global__ __launch_bounds__(256) void build_A_kernel(
    const float* __restrict__ params, const float* __restrict__ heating,
    const float* __restrict__ Bm, const float* __restrict__ tout_v,
    float* __restrict__ ws, float* __restrict__ out) {
    const int tid = threadIdx.x;
    float* A = ws + OFF_A;

    for (int idx = tid; idx < 130 * 130; idx += 256) {
        int r = idx / 130, c = idx - r * 130;
        A[r * NPAD + c] = sigm(params[idx]) * 1e-5f;
    }
    for (int r = tid; r < 130; r += 256) { A[r * NPAD + 130] = 0.f; A[r * NPAD + 131] = 0.f; }
    __syncthreads();
    for (int r = tid; r < 130; r += 256) {
        float s = 0.0f;
        for (int k = 0; k < 130; ++k) s += A[r * NPAD + k];
        A[r * NPAD + r] = -s;
    }
    for (int i = tid; i < 128; i += 256) {
        float bd = Bm[(2 + i) * 129 + (1 + i)];
        ws[OFF_AMP + i] = sigm(heating[i * 3]) * 500.0f * bd;
        float ph = heating[i * 3 + 1];
        ws[OFF_CPH + i] = cosf(ph);
        ws[OFF_SPH + i] = sinf(ph);
        ws[OFF_SH + i]  = heating[i * 3 + 2];
    }
    float iv = tout_v[0] + 4.0f;
    for (int i = tid; i < 128; i += 256) out[i] = iv;
    for (int r = tid; r < 130; r += 256) ws[OFF_XB + r] = iv;
}

// ---------------- mm: dst = X*Y (130x130), one block per output row ----------
__global__ __launch_bounds__(192) void mm_kernel(float* __restrict__ ws,
                                                 int offD, int offX, int offY) {
    const float* X = ws + offX;
    const float* Y = ws + offY;
    float* dst = ws + offD;
    __shared__ float xrow[130];
    const int r = blockIdx.x;
    const int c = threadIdx.x;
    if (c < 130) xrow[c] = X[r * NPAD + c];
    __syncthreads();
    if (c < 130) {
        float acc = 0.0f;
#pragma unroll 10
        for (int k = 0; k < 130; ++k)
            acc = fmaf(xrow[k], Y[k * NPAD + c], acc);
        dst[r * NPAD + c] = acc;
    }
    if (c >= 130 && c < 132) dst[r * NPAD + c] = 0.0f;
}

// ---------------- mm34: A3 = A*A2 (blocks 0..129), A4 = A2*A2 (130..259) -----
__global__ __launch_bounds__(192) void mm34_kernel(float* __restrict__ ws) {
    const int b = blockIdx.x;
    const bool hi = (b >= 130);
    const int r = hi ? b - 130 : b;
    const float* X = ws + (hi ? OFF_A2 : OFF_A);
    const float* Y = ws + OFF_A2;
    float* dst = ws + (hi ? OFF_P2 : OFF_A3);
    __shared__ float xrow[130];
    const int c = threadIdx.x;
    if (c < 130) xrow[c] = X[r * NPAD + c];
    __syncthreads();
    if (c < 130) {
        float acc = 0.0f;
#pragma unroll 10
        for (int k = 0; k < 130; ++k)
            acc = fmaf(xrow[k], Y[k * NPAD + c], acc);
        dst[r * NPAD + c] = acc;
    }
    if (c >= 130 && c < 132) dst[r * NPAD + c] = 0.0f;
}

// ---------------- combine: M, C1, C2 (+ transposed room blocks) --------------
__global__ __launch_bounds__(256) void combine_kernel(float* __restrict__ ws) {
    int idx = blockIdx.x * 256 + threadIdx.x;
    if (idx >= 130 * 130) return;
    int r = idx / 130, c = idx - r * 130;
    int o = r * NPAD + c;
    const float* A  = ws + OFF_A;
    const float* A2 = ws + OFF_A2;
    const float* A3 = ws + OFF_A3;
    const float* A4 = ws + OFF_P2;
    float eye = (r == c) ? 1.0f : 0.0f;
    float a = A[o], a2 = A2[o], a3 = A3[o], a4 = A4[o];
    float c1v = 5.0f * eye + 150.0f * a + 2250.0f * a2 + 33750.0f * a3;
    float c2v = 20.0f * eye + 300.0f * a + 2250.0f * a2;
    ws[OFF_M  + o] = eye + 30.0f * a + 450.0f * a2 + 4500.0f * a3 + 33750.0f * a4;
    ws[OFF_C1 + o] = c1v;
    ws[OFF_C2 + o] = c2v;
    if (r >= 2 && c >= 2) {   // transposed room sub-blocks for coalesced gper
        ws[OFF_C1T + (c - 2) * 128 + (r - 2)] = c1v;
        ws[OFF_C2T + (c - 2) * 128 + (r - 2)] = c2v;
    }
    if (c == 0) {
        ws[OFF_M + r * NPAD + 130] = 0.f; ws[OFF_M + r * NPAD + 131] = 0.f;
        ws[OFF_C1 + r * NPAD + 130] = 0.f; ws[OFF_C1 + r * NPAD + 131] = 0.f;
        ws[OFF_C2 + r * NPAD + 130] = 0.f; ws[OFF_C2 + r * NPAD + 131] = 0.f;
    }
}

// ---------------- vecs: c1b = C1*b0, c2b = C2*b0, c3b = (h/6) b0 -------------
__global__ __launch_bounds__(192) void vecs_kernel(const float* __restrict__ Bm,
                                                   float* __restrict__ ws) {
    const int r = threadIdx.x;
    if (r >= 130) return;
    const float* C1 = ws + OFF_C1;
    const float* C2 = ws + OFF_C2;
    float s1 = 0.0f, s2 = 0.0f;
    for (int k = 0; k < 130; ++k) {
        float b0 = Bm[k * 129];
        s1 = fmaf(C1[r * NPAD + k], b0, s1);
        s2 = fmaf(C2[r * NPAD + k], b0, s2);
    }
    ws[OFF_C1B + r] = s1;
    ws[OFF_C2B + r] = s2;
    ws[OFF_C3B + r] = 5.0f * Bm[r * 129];
}

// ---------------- gper: periodic forcing part P[m][r], m=0..2879 -------------
__global__ __launch_bounds__(256) void gper_kernel(float* __restrict__ ws) {
    const int tid = threadIdx.x;
    const int n0 = blockIdx.x * 32;
    const float* C1T = ws + OFF_C1T;
    const float* C2T = ws + OFF_C2T;
    const float* C1 = ws + OFF_C1;
    const float* C2 = ws + OFF_C2;
    const float* amp = ws + OFF_AMP;
    const float* cph = ws + OFF_CPH;
    const float* sph = ws + OFF_SPH;
    const float* sh  = ws + OFF_SH;
    float* P = ws + OFF_GP;

    __shared__ __align__(16) float qgT[128][36];
    __shared__ __align__(16) float qmT[128][36];
    __shared__ float sth[65], cth[65];

    for (int j = tid; j < 65; j += 256) {
        float t = (j < 33) ? (float)(n0 + j) * 30.0f
                           : (float)(n0 + j - 33) * 30.0f + 15.0f;
        float a = t * OMEGA;
        sth[j] = sinf(a);
        cth[j] = cosf(a);
    }
    __syncthreads();

    for (int p = tid; p < 65 * 128; p += 256) {
        int j = p >> 7, i = p & 127;
        float s = sth[j] * cph[i] + cth[j] * sph[i];
        float v = amp[i] / (1.0f + __expf(-sh[i] * s));
        if (j < 33) qgT[i][j] = v; else qmT[i][j - 33] = v;
    }
    __syncthreads();

    const int rr = tid & 127;
    const int half = tid >> 7;
    const int r = rr + 2;
    float acc1[16], acc2[16];
#pragma unroll
    for (int w = 0; w < 16; ++w) { acc1[w] = 0.0f; acc2[w] = 0.0f; }

    for (int k = 0; k < 128; ++k) {
        float c1 = C1T[(k << 7) + rr];
        float c2 = C2T[(k << 7) + rr];
        const float4* q1p = reinterpret_cast<const float4*>(&qgT[k][half * 16]);
        const float4* q2p = reinterpret_cast<const float4*>(&qmT[k][half * 16]);
#pragma unroll
        for (int w = 0; w < 4; ++w) {
            float4 a = q1p[w];
            float4 b = q2p[w];
            acc1[4 * w + 0] = fmaf(c1, a.x, acc1[4 * w + 0]);
            acc1[4 * w + 1] = fmaf(c1, a.y, acc1[4 * w + 1]);
            acc1[4 * w + 2] = fmaf(c1, a.z, acc1[4 * w + 2]);
            acc1[4 * w + 3] = fmaf(c1, a.w, acc1[4 * w + 3]);
            acc2[4 * w + 0] = fmaf(c2, b.x, acc2[4 * w + 0]);
            acc2[4 * w + 1] = fmaf(c2, b.y, acc2[4 * w + 1]);
            acc2[4 * w + 2] = fmaf(c2, b.z, acc2[4 * w + 2]);
            acc2[4 * w + 3] = fmaf(c2, b.w, acc2[4 * w + 3]);
        }
    }
#pragma unroll
    for (int w = 0; w < 16; ++w) {
        int n = half * 16 + w;
        P[(n0 + n) * 130 + r] = acc1[w] + acc2[w] + 5.0f * qgT[rr][n + 1];
    }

    if (tid < 64) {
        int r2 = tid >> 5;
        int n = tid & 31;
        float acc = 0.0f;
        for (int k = 0; k < 128; ++k) {
            acc = fmaf(C1[r2 * NPAD + 2 + k], qgT[k][n], acc);
            acc = fmaf(C2[r2 * NPAD + 2 + k], qmT[k][n], acc);
        }
        P[(n0 + n) * 130 + r2] = acc;
    }
}

// ---------------- ttab: (tg, tm) per step ------------------------------------
__global__ __launch_bounds__(256) void ttab_kernel(const float* __restrict__ tout_v,
                                                   float* __restrict__ ws) {
    int n = blockIdx.x * 256 + threadIdx.x;
    if (n < 131072) {
        float t = (float)n * 30.0f;
        float2* TT = reinterpret_cast<float2*>(ws + OFF_TT);
        TT[n] = make_float2(interp_tout(t, tout_v), interp_tout(t + 15.0f, tout_v));
    }
}

// ---------------- chunk_accum: G_c (+ S128 partial), g rebuilt on the fly ----
__global__ __launch_bounds__(192) void chunk_accum_kernel(float* __restrict__ ws) {
    const int c = blockIdx.x;
    const int r = threadIdx.x;
    const float* Mm = ws + OFF_M;
    const float* P = ws + OFF_GP;
    const float2* TT = reinterpret_cast<const float2*>(ws + OFF_TT);

    __shared__ __align__(16) float xs[2][132];
    float4 mr[33];
    float c1br = 0.f, c2br = 0.f, c3br = 0.f;
    if (r < 130) {
#pragma unroll
        for (int q = 0; q < 33; ++q)
            mr[q] = reinterpret_cast<const float4*>(&Mm[r * NPAD])[q];
        c1br = ws[OFF_C1B + r]; c2br = ws[OFF_C2B + r]; c3br = ws[OFF_C3B + r];
    } else {
#pragma unroll
        for (int q = 0; q < 33; ++q) mr[q] = make_float4(0.f, 0.f, 0.f, 0.f);
    }
    if (r < 132) { xs[0][r] = 0.0f; xs[1][r] = 0.0f; }
    __syncthreads();

    const int base = c * LCH;
    const int len = min(LCH, TSTEPS - base);
    int m = base % PERIOD;
    float pv = (r < 130) ? P[m * 130 + r] : 0.0f;
    float2 tc = TT[base], tn = TT[base + 1];
    int cur = 0;
    for (int j = 0; j < len; ++j) {
        if (r < 130) {
            float gcur = pv + tc.x * c1br + tc.y * c2br + tn.x * c3br;
            m = (m + 1 == PERIOD) ? 0 : m + 1;
            if (j + 1 < len) { pv = P[m * 130 + r]; tc = tn; tn = TT[base + j + 2]; }
            const float4* xp = reinterpret_cast<const float4*>(xs[cur]);
            float a0 = 0.f, a1 = 0.f, a2 = 0.f, a3 = 0.f;
#pragma unroll
            for (int q = 0; q < 33; ++q) {
                float4 xv = xp[q];
                a0 = fmaf(mr[q].x, xv.x, a0);
                a1 = fmaf(mr[q].y, xv.y, a1);
                a2 = fmaf(mr[q].z, xv.z, a2);
                a3 = fmaf(mr[q].w, xv.w, a3);
            }
            float val = (a0 + a1) + (a2 + a3) + gcur;
            xs[cur ^ 1][r] = val;
            if (j == 127) ws[OFF_S128 + c * 130 + r] = val;
        }
        __syncthreads();
        cur ^= 1;
    }
    if (r < 130) ws[OFF_G + c * 130 + r] = xs[cur][r];
}

// ---------------- superaccum: SA_s = sum MP^{15-i} G[16s+i], s=0..30 ----------
__global__ __launch_bounds__(192) void superaccum_kernel(float* __restrict__ ws) {
    const int s = blockIdx.x;
    const int r = threadIdx.x;
    const float* MP = ws + OFF_MP;
    const float* G = ws + OFF_G;

    __shared__ __align__(16) float xs[2][132];
    float4 mr[33];
    if (r < 130) {
#pragma unroll
        for (int q = 0; q < 33; ++q)
            mr[q] = reinterpret_cast<const float4*>(&MP[r * NPAD])[q];
    } else {
#pragma unroll
        for (int q = 0; q < 33; ++q) mr[q] = make_float4(0.f, 0.f, 0.f, 0.f);
    }
    if (r < 132) { xs[0][r] = 0.0f; xs[1][r] = 0.0f; }
    __syncthreads();

    int cur = 0;
    for (int i = 0; i < 16; ++i) {
        if (r < 130) {
            const float4* xp = reinterpret_cast<const float4*>(xs[cur]);
            float a0 = 0.f, a1 = 0.f, a2 = 0.f, a3 = 0.f;
#pragma unroll
            for (int q = 0; q < 33; ++q) {
                float4 xv = xp[q];
                a0 = fmaf(mr[q].x, xv.x, a0);
                a1 = fmaf(mr[q].y, xv.y, a1);
                a2 = fmaf(mr[q].z, xv.z, a2);
                a3 = fmaf(mr[q].w, xv.w, a3);
            }
            xs[cur ^ 1][r] = (a0 + a1) + (a2 + a3) + G[(16 * s + i) * 130 + r];
        }
        __syncthreads();
        cur ^= 1;
    }
    if (r < 130) ws[OFF_SA + s * 130 + r] = xs[cur][r];
}

// ---------------- superbound: xb[16(s+1)] = M4K xb[16s] + SA_s (serial) -------
__global__ __launch_bounds__(192) void superbound_kernel(float* __restrict__ ws) {
    const int r = threadIdx.x;
    const float* M4K = ws + OFF_M4K;
    const float* SA = ws + OFF_SA;
    float* xb = ws + OFF_XB;

    __shared__ __align__(16) float xs[2][132];
    float4 mr[33];
    if (r < 130) {
#pragma unroll
        for (int q = 0; q < 33; ++q)
            mr[q] = reinterpret_cast<const float4*>(&M4K[r * NPAD])[q];
    } else {
#pragma unroll
        for (int q = 0; q < 33; ++q) mr[q] = make_float4(0.f, 0.f, 0.f, 0.f);
    }
    if (r < 132) { xs[0][r] = (r < 130) ? xb[r] : 0.0f; xs[1][r] = 0.0f; }
    __syncthreads();

    int cur = 0;
    for (int s = 0; s < 31; ++s) {
        if (r < 130) {
            const float4* xp = reinterpret_cast<const float4*>(xs[cur]);
            float a0 = 0.f, a1 = 0.f, a2 = 0.f, a3 = 0.f;
#pragma unroll
            for (int q = 0; q < 33; ++q) {
                float4 xv = xp[q];
                a0 = fmaf(mr[q].x, xv.x, a0);
                a1 = fmaf(mr[q].y, xv.y, a1);
                a2 = fmaf(mr[q].z, xv.z, a2);
                a3 = fmaf(mr[q].w, xv.w, a3);
            }
            float val = (a0 + a1) + (a2 + a3) + SA[s * 130 + r];
            xs[cur ^ 1][r] = val;
            xb[(16 * s + 16) * 130 + r] = val;
        }
        __syncthreads();
        cur ^= 1;
    }
}

// ---------------- chunkbound: walk 15 chunks within each superchunk ----------
__global__ __launch_bounds__(192) void chunkbound_kernel(float* __restrict__ ws) {
    const int s = blockIdx.x;
    const int r = threadIdx.x;
    const float* MP = ws + OFF_MP;
    const float* G = ws + OFF_G;
    float* xb = ws + OFF_XB;

    __shared__ __align__(16) float xs[2][132];
    float4 mr[33];
    if (r < 130) {
#pragma unroll
        for (int q = 0; q < 33; ++q)
            mr[q] = reinterpret_cast<const float4*>(&MP[r * NPAD])[q];
    } else {
#pragma unroll
        for (int q = 0; q < 33; ++q) mr[q] = make_float4(0.f, 0.f, 0.f, 0.f);
    }
    if (r < 132) { xs[0][r] = (r < 130) ? xb[(16 * s) * 130 + r] : 0.0f; xs[1][r] = 0.0f; }
    __syncthreads();

    int cur = 0;
    for (int i = 0; i < 15; ++i) {
        if (r < 130) {
            const float4* xp = reinterpret_cast<const float4*>(xs[cur]);
            float a0 = 0.f, a1 = 0.f, a2 = 0.f, a3 = 0.f;
#pragma unroll
            for (int q = 0; q < 33; ++q) {
                float4 xv = xp[q];
                a0 = fmaf(mr[q].x, xv.x, a0);
                a1 = fmaf(mr[q].y, xv.y, a1);
                a2 = fmaf(mr[q].z, xv.z, a2);
                a3 = fmaf(mr[q].w, xv.w, a3);
            }
            float val = (a0 + a1) + (a2 + a3) + G[(16 * s + i) * 130 + r];
            xs[cur ^ 1][r] = val;
            xb[(16 * s + i + 1) * 130 + r] = val;
        }
        __syncthreads();
        cur ^= 1;
    }
}

// ---------------- subbound: xb2[2c]=xb[c]; xb2[2c+1]=M128 xb[c]+S128[c] -------
__global__ __launch_bounds__(192) void subbound_kernel(float* __restrict__ ws) {
    const int c = blockIdx.x;
    const int r = threadIdx.x;
    const float* M128 = ws + OFF_M128;
    const float* xb = ws + OFF_XB;
    float* xb2 = ws + OFF_XB2;

    __shared__ __align__(16) float xs[132];
    if (r < 132) xs[r] = (r < 130) ? xb[c * 130 + r] : 0.0f;
    __syncthreads();
    if (r < 130) {
        const float4* xp = reinterpret_cast<const float4*>(xs);
        const float4* mp = reinterpret_cast<const float4*>(&M128[r * NPAD]);
        float a0 = 0.f, a1 = 0.f, a2 = 0.f, a3 = 0.f;
#pragma unroll
        for (int q = 0; q < 33; ++q) {
            float4 m = mp[q];
            float4 xv = xp[q];
            a0 = fmaf(m.x, xv.x, a0);
            a1 = fmaf(m.y, xv.y, a1);
            a2 = fmaf(m.z, xv.z, a2);
            a3 = fmaf(m.w, xv.w, a3);
        }
        xb2[(2 * c) * 130 + r] = xs[r];
        xb2[(2 * c + 1) * 130 + r] = (a0 + a1) + (a2 + a3) + ws[OFF_S128 + c * 130 + r];
    }
}

// ---------------- emit: 1024 half-chunks x <=128 steps, g on the fly ---------
__global__ __launch_bounds__(192) void chunk_emit_kernel(float* __restrict__ ws,
                                                         float* __restrict__ out) {
    const int ec = blockIdx.x;
    const int r = threadIdx.x;
    const float* Mm = ws + OFF_M;
    const float* P = ws + OFF_GP;
    const float2* TT = reinterpret_cast<const float2*>(ws + OFF_TT);
    const float* xb2 = ws + OFF_XB2;

    __shared__ __align__(16) float xs[2][132];
    float4 mr[33];
    float c1br = 0.f, c2br = 0.f, c3br = 0.f;
    if (r < 130) {
#pragma unroll
        for (int q = 0; q < 33; ++q)
            mr[q] = reinterpret_cast<const float4*>(&Mm[r * NPAD])[q];
        c1br = ws[OFF_C1B + r]; c2br = ws[OFF_C2B + r]; c3br = ws[OFF_C3B + r];
    } else {
#pragma unroll
        for (int q = 0; q < 33; ++q) mr[q] = make_float4(0.f, 0.f, 0.f, 0.f);
    }
    if (r < 132) { xs[0][r] = (r < 130) ? xb2[ec * 130 + r] : 0.0f; xs[1][r] = 0.0f; }
    __syncthreads();

    const int base = ec * 128;
    const int len = min(128, TSTEPS - base);
    int m = base % PERIOD;
    float pv = (r < 130) ? P[m * 130 + r] : 0.0f;
    float2 tc = TT[base], tn = TT[base + 1];
    int cur = 0;
    for (int j = 0; j < len; ++j) {
        if (r < 130) {
            float gcur = pv + tc.x * c1br + tc.y * c2br + tn.x * c3br;
            m = (m + 1 == PERIOD) ? 0 : m + 1;
            if (j + 1 < len) { pv = P[m * 130 + r]; tc = tn; tn = TT[base + j + 2]; }
            const float4* xp = reinterpret_cast<const float4*>(xs[cur]);
            float a0 = 0.f, a1 = 0.f, a2 = 0.f, a3 = 0.f;
#pragma unroll
            for (int q = 0; q < 33; ++q) {
                float4 xv = xp[q];
                a0 = fmaf(mr[q].x, xv.x, a0);
                a1 = fmaf(mr[q].y, xv.y, a1);
                a2 = fmaf(mr[q].z, xv.z, a2);
                a3 = fmaf(mr[q].w, xv.w, a3);
            }
            float val = (a0 + a1) + (a2 + a3) + gcur;
            xs[cur ^ 1][r] = val;
            if (r >= 2) out[(base + j + 1) * 128 + (r - 2)] = val;
        }
        __syncthreads();
        cur ^= 1;
    }
}

extern "C" void kernel_launch(void* const* d_in, const int* in_sizes, int n_in,
                              void* d_out, int out_size, void* d_ws, size_t ws_size,
                              hipStream_t stream) {
    const float* params  = (const float*)d_in[1];
    const float* heating = (const float*)d_in[2];
    const float* Bm      = (const float*)d_in[3];
    const float* tout_v  = (const float*)d_in[5];
    float* out = (float*)d_out;
    float* ws = (float*)d_ws;

    build_A_kernel<<<1, 256, 0, stream>>>(params, heating, Bm, tout_v, ws, out);

    mm_kernel<<<130, 192, 0, stream>>>(ws, OFF_A2, OFF_A, OFF_A);   // A^2
    mm34_kernel<<<260, 192, 0, stream>>>(ws);                       // A^3, A^4
    combine_kernel<<<67, 256, 0, stream>>>(ws);                     // M,C1,C2,+T
    vecs_kernel<<<1, 192, 0, stream>>>(Bm, ws);
    gper_kernel<<<90, 256, 0, stream>>>(ws);                        // periodic P
    ttab_kernel<<<512, 256, 0, stream>>>(tout_v, ws);               // tout tables

    // squarings: M^2..M^4096
    mm_kernel<<<130, 192, 0, stream>>>(ws, OFF_P1,   OFF_M,    OFF_M);    // M^2
    mm_kernel<<<130, 192, 0, stream>>>(ws, OFF_P2,   OFF_P1,   OFF_P1);   // M^4
    mm_kernel<<<130, 192, 0, stream>>>(ws, OFF_P1,   OFF_P2,   OFF_P2);   // M^8
    mm_kernel<<<130, 192, 0, stream>>>(ws, OFF_P2,   OFF_P1,   OFF_P1);   // M^16
    mm_kernel<<<130, 192, 0, stream>>>(ws, OFF_P1,   OFF_P2,   OFF_P2);   // M^32
    mm_kernel<<<130, 192, 0, stream>>>(ws, OFF_P2,   OFF_P1,   OFF_P1);   // M^64
    mm_kernel<<<130, 192, 0, stream>>>(ws, OFF_M128, OFF_P2,   OFF_P2);   // M^128
    mm_kernel<<<130, 192, 0, stream>>>(ws, OFF_MP,   OFF_M128, OFF_M128); // M^256
    mm_kernel<<<130, 192, 0, stream>>>(ws, OFF_P1,   OFF_MP,   OFF_MP);   // M^512
    mm_kernel<<<130, 192, 0, stream>>>(ws, OFF_P2,   OFF_P1,   OFF_P1);   // M^1024
    mm_kernel<<<130, 192, 0, stream>>>(ws, OFF_P1,   OFF_P2,   OFF_P2);   // M^2048
    mm_kernel<<<130, 192, 0, stream>>>(ws, OFF_M4K,  OFF_P1,   OFF_P1);   // M^4096

    chunk_accum_kernel<<<NCH, 192, 0, stream>>>(ws);
    superaccum_kernel<<<31, 192, 0, stream>>>(ws);
    superbound_kernel<<<1, 192, 0, stream>>>(ws);
    chunkbound_kernel<<<32, 192, 0, stream>>>(ws);
    subbound_kernel<<<NCH, 192, 0, stream>>>(ws);
    chunk_emit_kernel<<<2 * NCH, 192, 0, stream>>>(ws, out);
}